// Round 3
// baseline (288.229 us; speedup 1.0000x reference)
//
#include <hip/hip_runtime.h>
#include <math.h>

#define BATCH   128
#define NUSER   10000
#define NITEM   10000
#define EDIM    64
#define FUDIM   8
#define FIDIM   8
#define INDIM   144   // 2*EDIM + FUDIM + FIDIM

typedef float v4f __attribute__((ext_vector_type(4)));

// d_out layout (floats):
// [0, 8192)                      new_user        (B x E)
// [8192, 16384)                  new_item        (B x E)
// [16384, 16384+81920000)        new_user_memory (B x NU x E)
// [16384+81920000, ...)          new_item_memory (B x NI x E)
#define OFF_NI   ((long)BATCH * EDIM)
#define OFF_UM   ((long)2 * BATCH * EDIM)
#define MEM_ELTS ((long)BATCH * NUSER * EDIM)
#define OFF_IM   (OFF_UM + MEM_ELTS)

__global__ __launch_bounds__(256) void limnet_copy_kernel(
    const v4f* __restrict__ um, const v4f* __restrict__ im,
    v4f* __restrict__ out_um, v4f* __restrict__ out_im, long n4) {
    const long stride = (long)gridDim.x * blockDim.x;
    long i = (long)blockIdx.x * blockDim.x + threadIdx.x;

    // Main loop: 4x unroll, 8 independent loads in flight before any store.
    for (; i + 3 * stride < n4; i += 4 * stride) {
        const long i1 = i + stride, i2 = i + 2 * stride, i3 = i + 3 * stride;
        v4f a0 = __builtin_nontemporal_load(&um[i]);
        v4f a1 = __builtin_nontemporal_load(&um[i1]);
        v4f a2 = __builtin_nontemporal_load(&um[i2]);
        v4f a3 = __builtin_nontemporal_load(&um[i3]);
        v4f b0 = __builtin_nontemporal_load(&im[i]);
        v4f b1 = __builtin_nontemporal_load(&im[i1]);
        v4f b2 = __builtin_nontemporal_load(&im[i2]);
        v4f b3 = __builtin_nontemporal_load(&im[i3]);
        __builtin_nontemporal_store(a0, &out_um[i]);
        __builtin_nontemporal_store(a1, &out_um[i1]);
        __builtin_nontemporal_store(a2, &out_um[i2]);
        __builtin_nontemporal_store(a3, &out_um[i3]);
        __builtin_nontemporal_store(b0, &out_im[i]);
        __builtin_nontemporal_store(b1, &out_im[i1]);
        __builtin_nontemporal_store(b2, &out_im[i2]);
        __builtin_nontemporal_store(b3, &out_im[i3]);
    }
    // Tail.
    for (; i < n4; i += stride) {
        v4f a = __builtin_nontemporal_load(&um[i]);
        v4f b = __builtin_nontemporal_load(&im[i]);
        __builtin_nontemporal_store(a, &out_um[i]);
        __builtin_nontemporal_store(b, &out_im[i]);
    }
}

__global__ __launch_bounds__(64) void limnet_gru_kernel(
    const float* __restrict__ um, const float* __restrict__ im,
    const int* __restrict__ uids, const int* __restrict__ iids,
    const float* __restrict__ ufeat, const float* __restrict__ ifeat,
    const float* __restrict__ u_w_ih, const float* __restrict__ u_b_ih,
    const float* __restrict__ u_b_hh,
    const float* __restrict__ i_w_ih, const float* __restrict__ i_b_ih,
    const float* __restrict__ i_b_hh,
    float* __restrict__ out)
{
    const int unit  = blockIdx.x;   // 0..255
    const int b     = unit >> 1;
    const int which = unit & 1;     // 0 = user GRU, 1 = item GRU
    const int lane  = threadIdx.x;  // 0..63

    __shared__ float x[INDIM];

    const int uid = uids[b];
    const int iid = iids[b];
    const float* ue = um + ((long)b * NUSER + uid) * EDIM;
    const float* ie = im + ((long)b * NITEM + iid) * EDIM;

    // Build the 144-dim concatenated input in LDS.
    if (which == 0) {
        // [user_emb(64), user_feat(8), item_emb(64), item_feat(8)]
        x[lane] = ue[lane];
        x[EDIM + FUDIM + lane] = ie[lane];
        if (lane < FUDIM) x[EDIM + lane] = ufeat[b * FUDIM + lane];
        if (lane < FIDIM) x[EDIM + FUDIM + EDIM + lane] = ifeat[b * FIDIM + lane];
    } else {
        // [item_emb(64), item_feat(8), user_emb(64), user_feat(8)]
        x[lane] = ie[lane];
        x[EDIM + FIDIM + lane] = ue[lane];
        if (lane < FIDIM) x[EDIM + lane] = ifeat[b * FIDIM + lane];
        if (lane < FUDIM) x[EDIM + FIDIM + EDIM + lane] = ufeat[b * FUDIM + lane];
    }
    __syncthreads();

    const float* w   = which ? i_w_ih : u_w_ih;
    const float* bih = which ? i_b_ih : u_b_ih;
    const float* bhh = which ? i_b_hh : u_b_hh;

    // h0 == 0  =>  gh = b_hh exactly; GRU collapses to gates on gi only.
    float gr = bih[lane];
    float gz = bih[EDIM + lane];
    float gn = bih[2 * EDIM + lane];
    // Row base: lane*INDIM floats = lane*576 bytes -> 16B aligned, v4f ok.
    const v4f* wr = (const v4f*)(w + (long)lane * INDIM);
    const v4f* wz = (const v4f*)(w + (long)(EDIM + lane) * INDIM);
    const v4f* wn = (const v4f*)(w + (long)(2 * EDIM + lane) * INDIM);
    #pragma unroll 6
    for (int k4 = 0; k4 < INDIM / 4; ++k4) {
        const v4f vr = wr[k4];
        const v4f vz = wz[k4];
        const v4f vn = wn[k4];
        const float x0 = x[4 * k4 + 0], x1 = x[4 * k4 + 1];
        const float x2 = x[4 * k4 + 2], x3 = x[4 * k4 + 3];
        gr = fmaf(vr.x, x0, gr); gr = fmaf(vr.y, x1, gr);
        gr = fmaf(vr.z, x2, gr); gr = fmaf(vr.w, x3, gr);
        gz = fmaf(vz.x, x0, gz); gz = fmaf(vz.y, x1, gz);
        gz = fmaf(vz.z, x2, gz); gz = fmaf(vz.w, x3, gz);
        gn = fmaf(vn.x, x0, gn); gn = fmaf(vn.y, x1, gn);
        gn = fmaf(vn.z, x2, gn); gn = fmaf(vn.w, x3, gn);
    }
    const float r = 1.0f / (1.0f + expf(-(gr + bhh[lane])));
    const float z = 1.0f / (1.0f + expf(-(gz + bhh[EDIM + lane])));
    const float n = tanhf(gn + r * bhh[2 * EDIM + lane]);
    const float h = (1.0f - z) * n;     // + z*h0, h0 == 0

    // L2 normalize across the 64-lane wave.
    float s = h * h;
    #pragma unroll
    for (int off = 32; off; off >>= 1) s += __shfl_xor(s, off, 64);
    const float val = h / fmaxf(sqrtf(s), 1e-12f);

    if (which == 0) {
        out[(long)b * EDIM + lane] = val;
        out[OFF_UM + ((long)b * NUSER + uid) * EDIM + lane] = val;
    } else {
        out[OFF_NI + (long)b * EDIM + lane] = val;
        out[OFF_IM + ((long)b * NITEM + iid) * EDIM + lane] = val;
    }
}

extern "C" void kernel_launch(void* const* d_in, const int* in_sizes, int n_in,
                              void* d_out, int out_size, void* d_ws, size_t ws_size,
                              hipStream_t stream) {
    const float* um    = (const float*)d_in[0];
    const float* im    = (const float*)d_in[1];
    const int*   uids  = (const int*)d_in[2];
    const int*   iids  = (const int*)d_in[3];
    const float* ufeat = (const float*)d_in[4];
    const float* ifeat = (const float*)d_in[5];
    const float* u_w_ih = (const float*)d_in[6];
    // d_in[7] = u_w_hh (unused: h0 == 0)
    const float* u_b_ih = (const float*)d_in[8];
    const float* u_b_hh = (const float*)d_in[9];
    const float* i_w_ih = (const float*)d_in[10];
    // d_in[11] = i_w_hh (unused)
    const float* i_b_ih = (const float*)d_in[12];
    const float* i_b_hh = (const float*)d_in[13];
    float* out = (float*)d_out;

    // 1) Bulk copy of both memories into the output regions (the roofline).
    const long n4 = MEM_ELTS / 4;  // float4 count per memory
    limnet_copy_kernel<<<2048, 256, 0, stream>>>(
        (const v4f*)um, (const v4f*)im,
        (v4f*)(out + OFF_UM), (v4f*)(out + OFF_IM), n4);

    // 2) GRU + normalize + scatter-overwrite (tiny; ordered after the copy).
    limnet_gru_kernel<<<BATCH * 2, 64, 0, stream>>>(
        um, im, uids, iids, ufeat, ifeat,
        u_w_ih, u_b_ih, u_b_hh,
        i_w_ih, i_b_ih, i_b_hh,
        out);
}

// Round 4
// 286.695 us; speedup vs baseline: 1.0054x; 1.0054x over previous
//
#include <hip/hip_runtime.h>
#include <math.h>

#define BATCH   128
#define NUSER   10000
#define NITEM   10000
#define EDIM    64
#define FUDIM   8
#define FIDIM   8
#define INDIM   144   // 2*EDIM + FUDIM + FIDIM

typedef float v4f __attribute__((ext_vector_type(4)));

// d_out layout (floats):
// [0, 8192)                      new_user        (B x E)
// [8192, 16384)                  new_item        (B x E)
// [16384, 16384+81920000)        new_user_memory (B x NU x E)
// [16384+81920000, ...)          new_item_memory (B x NI x E)
#define OFF_NI   ((long)BATCH * EDIM)
#define OFF_UM   ((long)2 * BATCH * EDIM)
#define MEM_ELTS ((long)BATCH * NUSER * EDIM)
#define OFF_IM   (OFF_UM + MEM_ELTS)

// Single-stream copy, structurally identical to the m13 6.29 TB/s reference:
// one src base, one dst base, grid-stride, dwordx4. Mild 2x ILP.
__global__ __launch_bounds__(256) void limnet_copy_kernel(
    const v4f* __restrict__ src, v4f* __restrict__ dst, long n4) {
    const long stride = (long)gridDim.x * blockDim.x;
    long i = (long)blockIdx.x * blockDim.x + threadIdx.x;
    for (; i + stride < n4; i += 2 * stride) {
        v4f a = src[i];
        v4f b = src[i + stride];
        dst[i] = a;
        dst[i + stride] = b;
    }
    for (; i < n4; i += stride) {
        dst[i] = src[i];
    }
}

__global__ __launch_bounds__(64) void limnet_gru_kernel(
    const float* __restrict__ um, const float* __restrict__ im,
    const int* __restrict__ uids, const int* __restrict__ iids,
    const float* __restrict__ ufeat, const float* __restrict__ ifeat,
    const float* __restrict__ u_w_ih, const float* __restrict__ u_b_ih,
    const float* __restrict__ u_b_hh,
    const float* __restrict__ i_w_ih, const float* __restrict__ i_b_ih,
    const float* __restrict__ i_b_hh,
    float* __restrict__ out)
{
    const int unit  = blockIdx.x;   // 0..255
    const int b     = unit >> 1;
    const int which = unit & 1;     // 0 = user GRU, 1 = item GRU
    const int lane  = threadIdx.x;  // 0..63

    __shared__ float x[INDIM];

    const int uid = uids[b];
    const int iid = iids[b];
    const float* ue = um + ((long)b * NUSER + uid) * EDIM;
    const float* ie = im + ((long)b * NITEM + iid) * EDIM;

    // Build the 144-dim concatenated input in LDS.
    if (which == 0) {
        // [user_emb(64), user_feat(8), item_emb(64), item_feat(8)]
        x[lane] = ue[lane];
        x[EDIM + FUDIM + lane] = ie[lane];
        if (lane < FUDIM) x[EDIM + lane] = ufeat[b * FUDIM + lane];
        if (lane < FIDIM) x[EDIM + FUDIM + EDIM + lane] = ifeat[b * FIDIM + lane];
    } else {
        // [item_emb(64), item_feat(8), user_emb(64), user_feat(8)]
        x[lane] = ie[lane];
        x[EDIM + FIDIM + lane] = ue[lane];
        if (lane < FIDIM) x[EDIM + lane] = ifeat[b * FIDIM + lane];
        if (lane < FUDIM) x[EDIM + FIDIM + EDIM + lane] = ufeat[b * FUDIM + lane];
    }
    __syncthreads();

    const float* w   = which ? i_w_ih : u_w_ih;
    const float* bih = which ? i_b_ih : u_b_ih;
    const float* bhh = which ? i_b_hh : u_b_hh;

    // h0 == 0  =>  gh = b_hh exactly; GRU collapses to gates on gi only.
    float gr = bih[lane];
    float gz = bih[EDIM + lane];
    float gn = bih[2 * EDIM + lane];
    // Row base: lane*INDIM floats = lane*576 bytes -> 16B aligned, v4f ok.
    const v4f* wr = (const v4f*)(w + (long)lane * INDIM);
    const v4f* wz = (const v4f*)(w + (long)(EDIM + lane) * INDIM);
    const v4f* wn = (const v4f*)(w + (long)(2 * EDIM + lane) * INDIM);
    #pragma unroll 6
    for (int k4 = 0; k4 < INDIM / 4; ++k4) {
        const v4f vr = wr[k4];
        const v4f vz = wz[k4];
        const v4f vn = wn[k4];
        const float x0 = x[4 * k4 + 0], x1 = x[4 * k4 + 1];
        const float x2 = x[4 * k4 + 2], x3 = x[4 * k4 + 3];
        gr = fmaf(vr.x, x0, gr); gr = fmaf(vr.y, x1, gr);
        gr = fmaf(vr.z, x2, gr); gr = fmaf(vr.w, x3, gr);
        gz = fmaf(vz.x, x0, gz); gz = fmaf(vz.y, x1, gz);
        gz = fmaf(vz.z, x2, gz); gz = fmaf(vz.w, x3, gz);
        gn = fmaf(vn.x, x0, gn); gn = fmaf(vn.y, x1, gn);
        gn = fmaf(vn.z, x2, gn); gn = fmaf(vn.w, x3, gn);
    }
    const float r = 1.0f / (1.0f + expf(-(gr + bhh[lane])));
    const float z = 1.0f / (1.0f + expf(-(gz + bhh[EDIM + lane])));
    const float n = tanhf(gn + r * bhh[2 * EDIM + lane]);
    const float h = (1.0f - z) * n;     // + z*h0, h0 == 0

    // L2 normalize across the 64-lane wave.
    float s = h * h;
    #pragma unroll
    for (int off = 32; off; off >>= 1) s += __shfl_xor(s, off, 64);
    const float val = h / fmaxf(sqrtf(s), 1e-12f);

    if (which == 0) {
        out[(long)b * EDIM + lane] = val;
        out[OFF_UM + ((long)b * NUSER + uid) * EDIM + lane] = val;
    } else {
        out[OFF_NI + (long)b * EDIM + lane] = val;
        out[OFF_IM + ((long)b * NITEM + iid) * EDIM + lane] = val;
    }
}

extern "C" void kernel_launch(void* const* d_in, const int* in_sizes, int n_in,
                              void* d_out, int out_size, void* d_ws, size_t ws_size,
                              hipStream_t stream) {
    const float* um    = (const float*)d_in[0];
    const float* im    = (const float*)d_in[1];
    const int*   uids  = (const int*)d_in[2];
    const int*   iids  = (const int*)d_in[3];
    const float* ufeat = (const float*)d_in[4];
    const float* ifeat = (const float*)d_in[5];
    const float* u_w_ih = (const float*)d_in[6];
    // d_in[7] = u_w_hh (unused: h0 == 0)
    const float* u_b_ih = (const float*)d_in[8];
    const float* u_b_hh = (const float*)d_in[9];
    const float* i_w_ih = (const float*)d_in[10];
    // d_in[11] = i_w_hh (unused)
    const float* i_b_ih = (const float*)d_in[12];
    const float* i_b_hh = (const float*)d_in[13];
    float* out = (float*)d_out;

    // 1) Two single-stream bulk copies (the roofline). Sequential launches;
    //    each saturates HBM alone with one src + one dst stream per wave.
    const long n4 = MEM_ELTS / 4;  // float4 count per memory
    limnet_copy_kernel<<<2048, 256, 0, stream>>>(
        (const v4f*)um, (v4f*)(out + OFF_UM), n4);
    limnet_copy_kernel<<<2048, 256, 0, stream>>>(
        (const v4f*)im, (v4f*)(out + OFF_IM), n4);

    // 2) GRU + normalize + scatter-overwrite (tiny; ordered after the copies).
    limnet_gru_kernel<<<BATCH * 2, 64, 0, stream>>>(
        um, im, uids, iids, ufeat, ifeat,
        u_w_ih, u_b_ih, u_b_hh,
        i_w_ih, i_b_ih, i_b_hh,
        out);
}

// Round 5
// 260.577 us; speedup vs baseline: 1.1061x; 1.1002x over previous
//
#include <hip/hip_runtime.h>
#include <math.h>

#define BATCH   128
#define NUSER   10000
#define NITEM   10000
#define EDIM    64
#define FUDIM   8
#define FIDIM   8
#define INDIM   144   // 2*EDIM + FUDIM + FIDIM

typedef float v4f __attribute__((ext_vector_type(4)));

// d_out layout (floats):
// [0, 8192)                      new_user        (B x E)
// [8192, 16384)                  new_item        (B x E)
// [16384, 16384+81920000)        new_user_memory (B x NU x E)
// [16384+81920000, ...)          new_item_memory (B x NI x E)
#define OFF_NI   ((long)BATCH * EDIM)
#define OFF_UM   ((long)2 * BATCH * EDIM)
#define MEM_ELTS ((long)BATCH * NUSER * EDIM)
#define OFF_IM   (OFF_UM + MEM_ELTS)

__global__ __launch_bounds__(64) void limnet_gru_kernel(
    const float* __restrict__ um, const float* __restrict__ im,
    const int* __restrict__ uids, const int* __restrict__ iids,
    const float* __restrict__ ufeat, const float* __restrict__ ifeat,
    const float* __restrict__ u_w_ih, const float* __restrict__ u_b_ih,
    const float* __restrict__ u_b_hh,
    const float* __restrict__ i_w_ih, const float* __restrict__ i_b_ih,
    const float* __restrict__ i_b_hh,
    float* __restrict__ out)
{
    const int unit  = blockIdx.x;   // 0..255
    const int b     = unit >> 1;
    const int which = unit & 1;     // 0 = user GRU, 1 = item GRU
    const int lane  = threadIdx.x;  // 0..63

    __shared__ float x[INDIM];

    const int uid = uids[b];
    const int iid = iids[b];
    const float* ue = um + ((long)b * NUSER + uid) * EDIM;
    const float* ie = im + ((long)b * NITEM + iid) * EDIM;

    // Build the 144-dim concatenated input in LDS.
    if (which == 0) {
        // [user_emb(64), user_feat(8), item_emb(64), item_feat(8)]
        x[lane] = ue[lane];
        x[EDIM + FUDIM + lane] = ie[lane];
        if (lane < FUDIM) x[EDIM + lane] = ufeat[b * FUDIM + lane];
        if (lane < FIDIM) x[EDIM + FUDIM + EDIM + lane] = ifeat[b * FIDIM + lane];
    } else {
        // [item_emb(64), item_feat(8), user_emb(64), user_feat(8)]
        x[lane] = ie[lane];
        x[EDIM + FIDIM + lane] = ue[lane];
        if (lane < FIDIM) x[EDIM + lane] = ifeat[b * FIDIM + lane];
        if (lane < FUDIM) x[EDIM + FIDIM + EDIM + lane] = ufeat[b * FUDIM + lane];
    }
    __syncthreads();

    const float* w   = which ? i_w_ih : u_w_ih;
    const float* bih = which ? i_b_ih : u_b_ih;
    const float* bhh = which ? i_b_hh : u_b_hh;

    // h0 == 0  =>  gh = b_hh exactly; GRU collapses to gates on gi only.
    float gr = bih[lane];
    float gz = bih[EDIM + lane];
    float gn = bih[2 * EDIM + lane];
    // Row base: lane*INDIM floats = lane*576 bytes -> 16B aligned, v4f ok.
    const v4f* wr = (const v4f*)(w + (long)lane * INDIM);
    const v4f* wz = (const v4f*)(w + (long)(EDIM + lane) * INDIM);
    const v4f* wn = (const v4f*)(w + (long)(2 * EDIM + lane) * INDIM);
    #pragma unroll 6
    for (int k4 = 0; k4 < INDIM / 4; ++k4) {
        const v4f vr = wr[k4];
        const v4f vz = wz[k4];
        const v4f vn = wn[k4];
        const float x0 = x[4 * k4 + 0], x1 = x[4 * k4 + 1];
        const float x2 = x[4 * k4 + 2], x3 = x[4 * k4 + 3];
        gr = fmaf(vr.x, x0, gr); gr = fmaf(vr.y, x1, gr);
        gr = fmaf(vr.z, x2, gr); gr = fmaf(vr.w, x3, gr);
        gz = fmaf(vz.x, x0, gz); gz = fmaf(vz.y, x1, gz);
        gz = fmaf(vz.z, x2, gz); gz = fmaf(vz.w, x3, gz);
        gn = fmaf(vn.x, x0, gn); gn = fmaf(vn.y, x1, gn);
        gn = fmaf(vn.z, x2, gn); gn = fmaf(vn.w, x3, gn);
    }
    const float r = 1.0f / (1.0f + expf(-(gr + bhh[lane])));
    const float z = 1.0f / (1.0f + expf(-(gz + bhh[EDIM + lane])));
    const float n = tanhf(gn + r * bhh[2 * EDIM + lane]);
    const float h = (1.0f - z) * n;     // + z*h0, h0 == 0

    // L2 normalize across the 64-lane wave.
    float s = h * h;
    #pragma unroll
    for (int off = 32; off; off >>= 1) s += __shfl_xor(s, off, 64);
    const float val = h / fmaxf(sqrtf(s), 1e-12f);

    if (which == 0) {
        out[(long)b * EDIM + lane] = val;
        out[OFF_UM + ((long)b * NUSER + uid) * EDIM + lane] = val;
    } else {
        out[OFF_NI + (long)b * EDIM + lane] = val;
        out[OFF_IM + ((long)b * NITEM + iid) * EDIM + lane] = val;
    }
}

extern "C" void kernel_launch(void* const* d_in, const int* in_sizes, int n_in,
                              void* d_out, int out_size, void* d_ws, size_t ws_size,
                              hipStream_t stream) {
    const float* um    = (const float*)d_in[0];
    const float* im    = (const float*)d_in[1];
    const int*   uids  = (const int*)d_in[2];
    const int*   iids  = (const int*)d_in[3];
    const float* ufeat = (const float*)d_in[4];
    const float* ifeat = (const float*)d_in[5];
    const float* u_w_ih = (const float*)d_in[6];
    // d_in[7] = u_w_hh (unused: h0 == 0)
    const float* u_b_ih = (const float*)d_in[8];
    const float* u_b_hh = (const float*)d_in[9];
    const float* i_w_ih = (const float*)d_in[10];
    // d_in[11] = i_w_hh (unused)
    const float* i_b_ih = (const float*)d_in[12];
    const float* i_b_hh = (const float*)d_in[13];
    float* out = (float*)d_out;

    // 1) Bulk copies via the runtime's D2D path (SDMA/blit) — A/B against
    //    shader-based copies, which plateaued at ~4.8 TB/s.
    const size_t mem_bytes = (size_t)MEM_ELTS * sizeof(float);
    hipMemcpyAsync(out + OFF_UM, um, mem_bytes, hipMemcpyDeviceToDevice, stream);
    hipMemcpyAsync(out + OFF_IM, im, mem_bytes, hipMemcpyDeviceToDevice, stream);

    // 2) GRU + normalize + scatter-overwrite (tiny; ordered after the copies).
    limnet_gru_kernel<<<BATCH * 2, 64, 0, stream>>>(
        um, im, uids, iids, ufeat, ifeat,
        u_w_ih, u_b_ih, u_b_hh,
        i_w_ih, i_b_ih, i_b_hh,
        out);
}

// Round 6
// 231.741 us; speedup vs baseline: 1.2438x; 1.1244x over previous
//
#include <hip/hip_runtime.h>
#include <math.h>

#define BATCH   128
#define NUSER   10000
#define NITEM   10000
#define EDIM    64
#define FUDIM   8
#define FIDIM   8
#define INDIM   144   // 2*EDIM + FUDIM + FIDIM

typedef float v4f __attribute__((ext_vector_type(4)));

// d_out layout (floats):
// [0, 8192)                      new_user        (B x E)
// [8192, 16384)                  new_item        (B x E)
// [16384, 16384+81920000)        new_user_memory (B x NU x E)
// [16384+81920000, ...)          new_item_memory (B x NI x E)
#define OFF_NI   ((long)BATCH * EDIM)
#define OFF_UM   ((long)2 * BATCH * EDIM)
#define MEM_ELTS ((long)BATCH * NUSER * EDIM)
#define OFF_IM   (OFF_UM + MEM_ELTS)

// m13-style one-shot copy: each thread moves exactly ONE float4, huge grid.
// MEM_ELTS/4 = 20,480,000 float4s -> 80,000 blocks x 256 threads, no loop.
__global__ __launch_bounds__(256) void limnet_copy_oneshot(
    const v4f* __restrict__ src, v4f* __restrict__ dst) {
    const long i = (long)blockIdx.x * 256 + threadIdx.x;
    dst[i] = src[i];
}

__global__ __launch_bounds__(64) void limnet_gru_kernel(
    const float* __restrict__ um, const float* __restrict__ im,
    const int* __restrict__ uids, const int* __restrict__ iids,
    const float* __restrict__ ufeat, const float* __restrict__ ifeat,
    const float* __restrict__ u_w_ih, const float* __restrict__ u_b_ih,
    const float* __restrict__ u_b_hh,
    const float* __restrict__ i_w_ih, const float* __restrict__ i_b_ih,
    const float* __restrict__ i_b_hh,
    float* __restrict__ out)
{
    const int unit  = blockIdx.x;   // 0..255
    const int b     = unit >> 1;
    const int which = unit & 1;     // 0 = user GRU, 1 = item GRU
    const int lane  = threadIdx.x;  // 0..63

    __shared__ float x[INDIM];

    const int uid = uids[b];
    const int iid = iids[b];
    const float* ue = um + ((long)b * NUSER + uid) * EDIM;
    const float* ie = im + ((long)b * NITEM + iid) * EDIM;

    // Build the 144-dim concatenated input in LDS.
    if (which == 0) {
        // [user_emb(64), user_feat(8), item_emb(64), item_feat(8)]
        x[lane] = ue[lane];
        x[EDIM + FUDIM + lane] = ie[lane];
        if (lane < FUDIM) x[EDIM + lane] = ufeat[b * FUDIM + lane];
        if (lane < FIDIM) x[EDIM + FUDIM + EDIM + lane] = ifeat[b * FIDIM + lane];
    } else {
        // [item_emb(64), item_feat(8), user_emb(64), user_feat(8)]
        x[lane] = ie[lane];
        x[EDIM + FIDIM + lane] = ue[lane];
        if (lane < FIDIM) x[EDIM + lane] = ifeat[b * FIDIM + lane];
        if (lane < FUDIM) x[EDIM + FIDIM + EDIM + lane] = ufeat[b * FUDIM + lane];
    }
    __syncthreads();

    const float* w   = which ? i_w_ih : u_w_ih;
    const float* bih = which ? i_b_ih : u_b_ih;
    const float* bhh = which ? i_b_hh : u_b_hh;

    // h0 == 0  =>  gh = b_hh exactly; GRU collapses to gates on gi only.
    float gr = bih[lane];
    float gz = bih[EDIM + lane];
    float gn = bih[2 * EDIM + lane];
    // Row base: lane*INDIM floats = lane*576 bytes -> 16B aligned, v4f ok.
    const v4f* wr = (const v4f*)(w + (long)lane * INDIM);
    const v4f* wz = (const v4f*)(w + (long)(EDIM + lane) * INDIM);
    const v4f* wn = (const v4f*)(w + (long)(2 * EDIM + lane) * INDIM);
    #pragma unroll 6
    for (int k4 = 0; k4 < INDIM / 4; ++k4) {
        const v4f vr = wr[k4];
        const v4f vz = wz[k4];
        const v4f vn = wn[k4];
        const float x0 = x[4 * k4 + 0], x1 = x[4 * k4 + 1];
        const float x2 = x[4 * k4 + 2], x3 = x[4 * k4 + 3];
        gr = fmaf(vr.x, x0, gr); gr = fmaf(vr.y, x1, gr);
        gr = fmaf(vr.z, x2, gr); gr = fmaf(vr.w, x3, gr);
        gz = fmaf(vz.x, x0, gz); gz = fmaf(vz.y, x1, gz);
        gz = fmaf(vz.z, x2, gz); gz = fmaf(vz.w, x3, gz);
        gn = fmaf(vn.x, x0, gn); gn = fmaf(vn.y, x1, gn);
        gn = fmaf(vn.z, x2, gn); gn = fmaf(vn.w, x3, gn);
    }
    const float r = 1.0f / (1.0f + expf(-(gr + bhh[lane])));
    const float z = 1.0f / (1.0f + expf(-(gz + bhh[EDIM + lane])));
    const float n = tanhf(gn + r * bhh[2 * EDIM + lane]);
    const float h = (1.0f - z) * n;     // + z*h0, h0 == 0

    // L2 normalize across the 64-lane wave.
    float s = h * h;
    #pragma unroll
    for (int off = 32; off; off >>= 1) s += __shfl_xor(s, off, 64);
    const float val = h / fmaxf(sqrtf(s), 1e-12f);

    if (which == 0) {
        out[(long)b * EDIM + lane] = val;
        out[OFF_UM + ((long)b * NUSER + uid) * EDIM + lane] = val;
    } else {
        out[OFF_NI + (long)b * EDIM + lane] = val;
        out[OFF_IM + ((long)b * NITEM + iid) * EDIM + lane] = val;
    }
}

extern "C" void kernel_launch(void* const* d_in, const int* in_sizes, int n_in,
                              void* d_out, int out_size, void* d_ws, size_t ws_size,
                              hipStream_t stream) {
    const float* um    = (const float*)d_in[0];
    const float* im    = (const float*)d_in[1];
    const int*   uids  = (const int*)d_in[2];
    const int*   iids  = (const int*)d_in[3];
    const float* ufeat = (const float*)d_in[4];
    const float* ifeat = (const float*)d_in[5];
    const float* u_w_ih = (const float*)d_in[6];
    // d_in[7] = u_w_hh (unused: h0 == 0)
    const float* u_b_ih = (const float*)d_in[8];
    const float* u_b_hh = (const float*)d_in[9];
    const float* i_w_ih = (const float*)d_in[10];
    // d_in[11] = i_w_hh (unused)
    const float* i_b_ih = (const float*)d_in[12];
    const float* i_b_hh = (const float*)d_in[13];
    float* out = (float*)d_out;

    // 1) One-shot m13-style copies: 1 float4 per thread, 80000-block grid.
    const int nblk = (int)(MEM_ELTS / 4 / 256);  // 80,000
    limnet_copy_oneshot<<<nblk, 256, 0, stream>>>(
        (const v4f*)um, (v4f*)(out + OFF_UM));
    limnet_copy_oneshot<<<nblk, 256, 0, stream>>>(
        (const v4f*)im, (v4f*)(out + OFF_IM));

    // 2) GRU + normalize + scatter-overwrite (tiny; ordered after the copies).
    limnet_gru_kernel<<<BATCH * 2, 64, 0, stream>>>(
        um, im, uids, iids, ufeat, ifeat,
        u_w_ih, u_b_ih, u_b_hh,
        i_w_ih, i_b_ih, i_b_hh,
        out);
}

// Round 7
// 208.621 us; speedup vs baseline: 1.3816x; 1.1108x over previous
//
#include <hip/hip_runtime.h>
#include <math.h>

#define BATCH   128
#define NUSER   10000
#define NITEM   10000
#define EDIM    64
#define FUDIM   8
#define FIDIM   8
#define INDIM   144   // 2*EDIM + FUDIM + FIDIM

typedef float v4f __attribute__((ext_vector_type(4)));

// d_out layout (floats):
// [0, 8192)                      new_user        (B x E)
// [8192, 16384)                  new_item        (B x E)
// [16384, 16384+81920000)        new_user_memory (B x NU x E)
// [16384+81920000, ...)          new_item_memory (B x NI x E)
#define OFF_NI   ((long)BATCH * EDIM)
#define OFF_UM   ((long)2 * BATCH * EDIM)
#define MEM_ELTS ((long)BATCH * NUSER * EDIM)
#define OFF_IM   (OFF_UM + MEM_ELTS)
#define NBLK_PER_MEM ((int)(MEM_ELTS / 4 / 256))   // 80,000

// Fused one-shot copy: each thread moves exactly ONE float4; first 80k
// blocks handle um, next 80k handle im. Nontemporal (streaming, no reuse).
__global__ __launch_bounds__(256) void limnet_copy_oneshot2(
    const v4f* __restrict__ um, v4f* __restrict__ out_um,
    const v4f* __restrict__ im, v4f* __restrict__ out_im) {
    int blk = blockIdx.x;
    const v4f* __restrict__ src = um;
    v4f* __restrict__ dst = out_um;
    if (blk >= NBLK_PER_MEM) {          // wave-uniform branch
        blk -= NBLK_PER_MEM;
        src = im;
        dst = out_im;
    }
    const long i = (long)blk * 256 + threadIdx.x;
    __builtin_nontemporal_store(__builtin_nontemporal_load(&src[i]), &dst[i]);
}

__global__ __launch_bounds__(64) void limnet_gru_kernel(
    const float* __restrict__ um, const float* __restrict__ im,
    const int* __restrict__ uids, const int* __restrict__ iids,
    const float* __restrict__ ufeat, const float* __restrict__ ifeat,
    const float* __restrict__ u_w_ih, const float* __restrict__ u_b_ih,
    const float* __restrict__ u_b_hh,
    const float* __restrict__ i_w_ih, const float* __restrict__ i_b_ih,
    const float* __restrict__ i_b_hh,
    float* __restrict__ out)
{
    const int unit  = blockIdx.x;   // 0..255
    const int b     = unit >> 1;
    const int which = unit & 1;     // 0 = user GRU, 1 = item GRU
    const int lane  = threadIdx.x;  // 0..63

    __shared__ float x[INDIM];

    const int uid = uids[b];
    const int iid = iids[b];
    const float* ue = um + ((long)b * NUSER + uid) * EDIM;
    const float* ie = im + ((long)b * NITEM + iid) * EDIM;

    // Build the 144-dim concatenated input in LDS.
    if (which == 0) {
        // [user_emb(64), user_feat(8), item_emb(64), item_feat(8)]
        x[lane] = ue[lane];
        x[EDIM + FUDIM + lane] = ie[lane];
        if (lane < FUDIM) x[EDIM + lane] = ufeat[b * FUDIM + lane];
        if (lane < FIDIM) x[EDIM + FUDIM + EDIM + lane] = ifeat[b * FIDIM + lane];
    } else {
        // [item_emb(64), item_feat(8), user_emb(64), user_feat(8)]
        x[lane] = ie[lane];
        x[EDIM + FIDIM + lane] = ue[lane];
        if (lane < FIDIM) x[EDIM + lane] = ifeat[b * FIDIM + lane];
        if (lane < FUDIM) x[EDIM + FIDIM + EDIM + lane] = ufeat[b * FUDIM + lane];
    }
    __syncthreads();

    const float* w   = which ? i_w_ih : u_w_ih;
    const float* bih = which ? i_b_ih : u_b_ih;
    const float* bhh = which ? i_b_hh : u_b_hh;

    // h0 == 0  =>  gh = b_hh exactly; GRU collapses to gates on gi only.
    float gr = bih[lane];
    float gz = bih[EDIM + lane];
    float gn = bih[2 * EDIM + lane];
    // Row base: lane*INDIM floats = lane*576 bytes -> 16B aligned, v4f ok.
    const v4f* wr = (const v4f*)(w + (long)lane * INDIM);
    const v4f* wz = (const v4f*)(w + (long)(EDIM + lane) * INDIM);
    const v4f* wn = (const v4f*)(w + (long)(2 * EDIM + lane) * INDIM);
    #pragma unroll 6
    for (int k4 = 0; k4 < INDIM / 4; ++k4) {
        const v4f vr = wr[k4];
        const v4f vz = wz[k4];
        const v4f vn = wn[k4];
        const float x0 = x[4 * k4 + 0], x1 = x[4 * k4 + 1];
        const float x2 = x[4 * k4 + 2], x3 = x[4 * k4 + 3];
        gr = fmaf(vr.x, x0, gr); gr = fmaf(vr.y, x1, gr);
        gr = fmaf(vr.z, x2, gr); gr = fmaf(vr.w, x3, gr);
        gz = fmaf(vz.x, x0, gz); gz = fmaf(vz.y, x1, gz);
        gz = fmaf(vz.z, x2, gz); gz = fmaf(vz.w, x3, gz);
        gn = fmaf(vn.x, x0, gn); gn = fmaf(vn.y, x1, gn);
        gn = fmaf(vn.z, x2, gn); gn = fmaf(vn.w, x3, gn);
    }
    const float r = 1.0f / (1.0f + expf(-(gr + bhh[lane])));
    const float z = 1.0f / (1.0f + expf(-(gz + bhh[EDIM + lane])));
    const float n = tanhf(gn + r * bhh[2 * EDIM + lane]);
    const float h = (1.0f - z) * n;     // + z*h0, h0 == 0

    // L2 normalize across the 64-lane wave.
    float s = h * h;
    #pragma unroll
    for (int off = 32; off; off >>= 1) s += __shfl_xor(s, off, 64);
    const float val = h / fmaxf(sqrtf(s), 1e-12f);

    if (which == 0) {
        out[(long)b * EDIM + lane] = val;
        out[OFF_UM + ((long)b * NUSER + uid) * EDIM + lane] = val;
    } else {
        out[OFF_NI + (long)b * EDIM + lane] = val;
        out[OFF_IM + ((long)b * NITEM + iid) * EDIM + lane] = val;
    }
}

extern "C" void kernel_launch(void* const* d_in, const int* in_sizes, int n_in,
                              void* d_out, int out_size, void* d_ws, size_t ws_size,
                              hipStream_t stream) {
    const float* um    = (const float*)d_in[0];
    const float* im    = (const float*)d_in[1];
    const int*   uids  = (const int*)d_in[2];
    const int*   iids  = (const int*)d_in[3];
    const float* ufeat = (const float*)d_in[4];
    const float* ifeat = (const float*)d_in[5];
    const float* u_w_ih = (const float*)d_in[6];
    // d_in[7] = u_w_hh (unused: h0 == 0)
    const float* u_b_ih = (const float*)d_in[8];
    const float* u_b_hh = (const float*)d_in[9];
    const float* i_w_ih = (const float*)d_in[10];
    // d_in[11] = i_w_hh (unused)
    const float* i_b_ih = (const float*)d_in[12];
    const float* i_b_hh = (const float*)d_in[13];
    float* out = (float*)d_out;

    // 1) Fused one-shot copy: 160k blocks, 1 float4/thread, NT hints.
    limnet_copy_oneshot2<<<2 * NBLK_PER_MEM, 256, 0, stream>>>(
        (const v4f*)um, (v4f*)(out + OFF_UM),
        (const v4f*)im, (v4f*)(out + OFF_IM));

    // 2) GRU + normalize + scatter-overwrite (tiny; ordered after the copy).
    limnet_gru_kernel<<<BATCH * 2, 64, 0, stream>>>(
        um, im, uids, iids, ufeat, ifeat,
        u_w_ih, u_b_ih, u_b_hh,
        i_w_ih, i_b_ih, i_b_hh,
        out);
}